// Round 9
// baseline (78.869 us; speedup 1.0000x reference)
//
#include <hip/hip_runtime.h>
#include <hip/hip_fp16.h>
#include <math.h>

#define BATCH 8
#define NSLOT 256
#define DDIM  256
#define HID   128
#define NREL  8

typedef _Float16 half8 __attribute__((ext_vector_type(8)));
typedef float float4v __attribute__((ext_vector_type(4)));

union U8 {
  uint32_t u[4];
  _Float16 f[8];
  half8 v;
  float4 f4;
};

union U4 {
  uint32_t u[2];
  _Float16 f[4];
  uint2 u2;
};

// ---------------------------------------------------------------------------
// R22: K-split proj — the last untouched invariant. Triangulated split: fill
// 42.5 (irreducible) + proj ~22-24 + pair ~10 + ~2 overhead. proj's slowness
// survives slot-pattern change (R20), W-pattern change (R0 projA), and cache
// warming (R21) — but ALL variants ran 8 waves/CU with a full K=256 chain per
// wave. Fix: block = one 16x16 tile, 4 waves each compute a K=64 partial
// (2 MFMA + 16 W-dwords + LDS slot slice), f32 partials reduced via 4KB LDS.
// 2048 blocks x 256 thr = 8 blocks/CU, 32 waves/CU (4x TLP, 1/4 chain).
// pair byte-identical to R14/R19/R20/R21 (validated session-best).
// d_ws: P f16[2048][256] at 0 (1 MB).
//
// MFMA maps (HW-validated R5-R12): A[m=lane&15][k=(lane>>4)*8+u],
//  B[k=(lane>>4)*8+u][n=lane&15], D[m=(lane>>4)*4+reg][n=lane&15].
// ---------------------------------------------------------------------------

// proj: P[r][c] = dot(slots[r], concatW[:,c]) + (c<128 ? b1[c] : 0)
//   concatW[k][c] = (c<128) ? W1[k][c] : W1[256+k][c-128]
// Block (cx, ry): rows ry*16..+15, cols cx*16..+15. Wave w: K in [w*64,w*64+64).
__global__ __launch_bounds__(256) void proj_kernel(
    const float* __restrict__ slots, const float* __restrict__ W1,
    const float* __restrict__ b1, _Float16* __restrict__ P) {
  __shared__ _Float16 SL[16 * 264];  // slot tile, 16 rows x (256+8 pad) f16
  __shared__ float RS[4 * 256];      // per-wave f32 partials [w][m*16+n]

  const int tid  = threadIdx.x;
  const int w    = tid >> 6;
  const int lane = tid & 63;
  const int lo16 = lane & 15;
  const int kg   = lane >> 4;
  const int row0 = blockIdx.y * 16;
  const int c0   = blockIdx.x * 16;
  const int c    = c0 + lo16;

  // ---- coalesced slot-tile loads (R20-validated): 4 float4/thread ----
  float4 sv[4];
  {
    const float* gbase = slots + (size_t)row0 * DDIM;
#pragma unroll
    for (int p = 0; p < 4; ++p) {
      const int idx = p * 256 + tid;
      sv[p] = *(const float4*)(gbase + (idx >> 6) * DDIM + (idx & 63) * 4);
    }
  }

  // ---- W B-frags for THIS WAVE'S K-chunk only: 16 strided dwords ----
  const float* Wcol =
      (c < HID) ? (W1 + c) : (W1 + (size_t)DDIM * HID + (c - HID));
  U8 bf[2];
#pragma unroll
  for (int s = 0; s < 2; ++s) {
    const int kb = w * 64 + s * 32 + kg * 8;
#pragma unroll
    for (int u = 0; u < 8; ++u)
      bf[s].f[u] = (_Float16)Wcol[(size_t)(kb + u) * HID];
  }

  // ---- cvt + LDS write of slot tile ----
#pragma unroll
  for (int p = 0; p < 4; ++p) {
    const int idx = p * 256 + tid;
    U4 h;
    h.f[0] = (_Float16)sv[p].x; h.f[1] = (_Float16)sv[p].y;
    h.f[2] = (_Float16)sv[p].z; h.f[3] = (_Float16)sv[p].w;
    *(uint2*)&SL[(idx >> 6) * 264 + (idx & 63) * 4] = h.u2;
  }

  __syncthreads();

  // ---- 2 MFMA over this wave's K-chunk ----
  float4v acc = {0.0f, 0.0f, 0.0f, 0.0f};
#pragma unroll
  for (int s = 0; s < 2; ++s) {
    U8 a;
    a.f4 = *(const float4*)&SL[lo16 * 264 + w * 64 + s * 32 + kg * 8];
    acc = __builtin_amdgcn_mfma_f32_16x16x32_f16(a.v, bf[s].v, acc, 0, 0, 0);
  }

  // ---- f32 partials to LDS: RS[w][(kg*4+reg)*16 + lo16] ----
#pragma unroll
  for (int reg = 0; reg < 4; ++reg)
    RS[w * 256 + (kg * 4 + reg) * 16 + lo16] = acc[reg];

  __syncthreads();

  // ---- cross-wave reduce + bias + store: thread t -> (m=t>>4, n=t&15) ----
  {
    const float s =
        RS[tid] + RS[256 + tid] + RS[512 + tid] + RS[768 + tid];
    const int m  = tid >> 4;
    const int cc = c0 + (tid & 15);
    const float bias = (cc < HID) ? b1[cc] : 0.0f;
    P[(size_t)(row0 + m) * 256 + cc] = (_Float16)(s + bias);
  }
}

// pair (byte-identical to R14/R19/R20/R21 session-best config)
// out[b,i,j,r] = sigmoid( sum_k relu(P[b,i,k]+P[b,j,128+k]) * W2[k,r] + b2[r] )
__global__ __launch_bounds__(256) void pair_kernel(
    const _Float16* __restrict__ P, const float* __restrict__ W2,
    const float* __restrict__ b2, float* __restrict__ out) {
  __shared__ uint32_t PiL[8 * 68];

  const int tid  = threadIdx.x;
  const int w    = tid >> 6;
  const int lane = tid & 63;
  const int n    = lane & 15;
  const int kg   = lane >> 4;

  const int b  = blockIdx.z;
  const int i0 = blockIdx.y * 8;
  const int j0 = blockIdx.x * 64 + w * 16;
  const _Float16* Pb = P + (size_t)b * NSLOT * 256;

  if (tid < 128) {  // stage Pi: 8 rows x 128 f16
    const int r  = tid >> 4;
    const int ch = tid & 15;
    const float4 t = *(const float4*)(Pb + (size_t)(i0 + r) * 256 + ch * 8);
    *(float4*)&PiL[r * 68 + ch * 4] = t;
  }

  U8 w2f[4];
#pragma unroll
  for (int kq = 0; kq < 4; ++kq) {
    const int kb = kq * 32 + kg * 8;
#pragma unroll
    for (int u = 0; u < 8; ++u) {
      const float v = W2[(kb + u) * NREL + (n & 7)];  // 4KB, L1-resident
      w2f[kq].f[u] = (n < NREL) ? (_Float16)v : (_Float16)0.0f;
    }
  }

  const float b2v = (n < NREL) ? b2[n & 7] : 0.0f;

  U8 pj[4];
#pragma unroll
  for (int kq = 0; kq < 4; ++kq)
    pj[kq].f4 =
        *(const float4*)(Pb + (size_t)(j0 + n) * 256 + HID + kq * 32 + kg * 8);

  __syncthreads();

#pragma unroll
  for (int i = 0; i < 8; ++i) {
    float4v acc = {0.0f, 0.0f, 0.0f, 0.0f};
#pragma unroll
    for (int kq = 0; kq < 4; ++kq) {
      U8 pi;
      pi.f4 = *(const float4*)&PiL[i * 68 + kq * 16 + kg * 4];  // broadcast
      U8 h;
      h.v = __builtin_elementwise_max(pj[kq].v + pi.v, (half8)(_Float16)0.0f);
      acc = __builtin_amdgcn_mfma_f32_16x16x32_f16(h.v, w2f[kq].v, acc, 0, 0, 0);
    }
    if (n < NREL) {
      float* obase =
          out + (((size_t)b * NSLOT + (i0 + i)) * NSLOT + j0) * NREL + n;
#pragma unroll
      for (int reg = 0; reg < 4; ++reg) {
        const int jrow = kg * 4 + reg;
        const float x = acc[reg] + b2v;
        obase[jrow * NREL] = __builtin_amdgcn_rcpf(1.0f + __expf(-x));
      }
    }
  }
}

extern "C" void kernel_launch(void* const* d_in, const int* in_sizes, int n_in,
                              void* d_out, int out_size, void* d_ws,
                              size_t ws_size, hipStream_t stream) {
  const float* slots = (const float*)d_in[0];  // [8,256,256]
  const float* W1    = (const float*)d_in[1];  // [512,128]
  const float* b1    = (const float*)d_in[2];  // [128]
  const float* W2    = (const float*)d_in[3];  // [128,8]
  const float* b2    = (const float*)d_in[4];  // [8]
  float* out  = (float*)d_out;                 // [8,256,256,8]
  _Float16* P = (_Float16*)d_ws;               // 1 MB

  proj_kernel<<<dim3(16, 128), 256, 0, stream>>>(slots, W1, b1, P);
  pair_kernel<<<dim3(NSLOT / 64, NSLOT / 8, BATCH), 256, 0, stream>>>(P, W2,
                                                                      b2, out);
}